// Round 1
// baseline (947.880 us; speedup 1.0000x reference)
//
#include <hip/hip_runtime.h>
#include <math.h>

// Problem constants
#define HW    4096          // 64*64
#define NTOT  16384         // B*HW
#define CKDIM 2304          // C*K = 256*9

// ws layout (float-element offsets)
#define WS_OFFS   0         // B*18*HW = 294912
#define WS_W00    294912    // each desc array: 9*16384 = 147456
#define WS_W01    442368
#define WS_W10    589824
#define WS_W11    737280
#define WS_I00    884736
#define WS_I01    1032192
#define WS_I10    1179648
#define WS_I11    1327104
#define WS_WFOLD  1474560   // 2304*256 = 589824
#define WS_BFOLD  2064384   // 256
// total = 2064640 floats = 8,258,560 bytes

// ---------------------------------------------------------------------------
// K1: offset conv. out channel layout (B, 18, Ho, Wo). One thread per element.
// ---------------------------------------------------------------------------
__global__ __launch_bounds__(256) void offset_conv_k(
    const float* __restrict__ x, const float* __restrict__ wof,
    const float* __restrict__ bof, float* __restrict__ offs) {
  const int tg  = blockIdx.x * 256 + threadIdx.x;   // ((b*18+oc)<<12) + sp
  const int sp  = tg & 4095;
  const int boc = tg >> 12;
  const int b   = boc / 18;
  const int oc  = boc - b * 18;
  const int ho  = sp >> 6, wo = sp & 63;
  float acc = bof[oc];
  const float* xb = x + ((long)(b << 8) << 12);     // b*256*4096
  const float* wb = wof + oc * 256 * 9;
  for (int c = 0; c < 256; ++c) {
    const float* xp = xb + (c << 12);
    const float* wp = wb + c * 9;
#pragma unroll
    for (int ky = 0; ky < 3; ++ky) {
      const int y = ho - 1 + ky;
      if (y < 0 || y > 63) continue;
#pragma unroll
      for (int kx = 0; kx < 3; ++kx) {
        const int xx = wo - 1 + kx;
        if (xx < 0 || xx > 63) continue;
        acc = fmaf(xp[(y << 6) + xx], wp[ky * 3 + kx], acc);
      }
    }
  }
  offs[tg] = acc;
}

// ---------------------------------------------------------------------------
// K2: per-sample descriptors. d = k*16384 + n, n = b*4096 + sp.
// 4 bilinear weights (validity folded in) + 4 clamped in-plane indices.
// ---------------------------------------------------------------------------
__global__ __launch_bounds__(256) void make_desc_k(
    const float* __restrict__ offs, float* __restrict__ ws) {
  const int d  = blockIdx.x * 256 + threadIdx.x;    // < 147456
  const int k  = d >> 14;
  const int n  = d & 16383;
  const int b  = n >> 12;
  const int sp = n & 4095;
  const int ho = sp >> 6, wo = sp & 63;
  const int ky = k / 3, kx = k - ky * 3;
  const float dy = offs[((b * 18 + (k << 1)) << 12) + sp];
  const float dx = offs[((b * 18 + (k << 1) + 1) << 12) + sp];
  const float py = (float)(ho - 1 + ky) + dy;
  const float px = (float)(wo - 1 + kx) + dx;
  const float y0f = floorf(py), x0f = floorf(px);
  const float ly = py - y0f, lx = px - x0f;
  const int y0 = (int)y0f, x0 = (int)x0f;
  const int y1 = y0 + 1, x1 = x0 + 1;
  const float vy0 = (y0 >= 0 && y0 < 64) ? 1.f : 0.f;
  const float vy1 = (y1 >= 0 && y1 < 64) ? 1.f : 0.f;
  const float vx0 = (x0 >= 0 && x0 < 64) ? 1.f : 0.f;
  const float vx1 = (x1 >= 0 && x1 < 64) ? 1.f : 0.f;
  const int y0c = min(max(y0, 0), 63), y1c = min(max(y1, 0), 63);
  const int x0c = min(max(x0, 0), 63), x1c = min(max(x1, 0), 63);
  ws[WS_W00 + d] = (1.f - ly) * (1.f - lx) * vy0 * vx0;
  ws[WS_W01 + d] = (1.f - ly) * lx * vy0 * vx1;
  ws[WS_W10 + d] = ly * (1.f - lx) * vy1 * vx0;
  ws[WS_W11 + d] = ly * lx * vy1 * vx1;
  int* iws = (int*)ws;
  iws[WS_I00 + d] = (y0c << 6) + x0c;
  iws[WS_I01 + d] = (y0c << 6) + x1c;
  iws[WS_I10 + d] = (y1c << 6) + x0c;
  iws[WS_I11 + d] = (y1c << 6) + x1c;
}

// ---------------------------------------------------------------------------
// K2b: fold weight to [i=k*256+c][o] with BN scale; fold bias.
// ---------------------------------------------------------------------------
__global__ __launch_bounds__(256) void fold_weight_k(
    const float* __restrict__ w, const float* __restrict__ bias,
    const float* __restrict__ gamma, const float* __restrict__ beta,
    const float* __restrict__ mean, const float* __restrict__ var,
    float* __restrict__ ws) {
  const int t = blockIdx.x * 256 + threadIdx.x;     // i*256 + o, i = k*256+c
  const int o = t & 255;
  const int i = t >> 8;
  const int k = i >> 8, c = i & 255;
  const float inv = gamma[o] * rsqrtf(var[o] + 1e-5f);
  ws[WS_WFOLD + t] = w[(((o << 8) + c) * 9) + k] * inv;
  if (t < 256) {
    ws[WS_BFOLD + t] = bias[o] * inv + beta[o] - mean[o] * inv;
  }
}

// ---------------------------------------------------------------------------
// K3: main GEMM with fused deformable im2col.
// C[o][n] = sum_{k,c} wfold[(k*256+c)][o] * sample(c,k,n); out = relu(C + bfold)
// Block tile: 64 (o) x 128 (n); 256 threads, 4x8 register tile; BK=16.
// ---------------------------------------------------------------------------
__global__ __launch_bounds__(256) void deform_gemm_k(
    const float* __restrict__ x, const float* __restrict__ ws,
    float* __restrict__ out) {
  __shared__ __align__(16) float As[16][64];
  __shared__ __align__(16) float Bs[16][128];
  const int t  = threadIdx.x;
  const int o0 = blockIdx.x << 6;
  const int n0 = blockIdx.y << 7;
  const int tx = t & 15, ty = t >> 4;

  float acc[4][8];
#pragma unroll
  for (int a = 0; a < 4; ++a)
#pragma unroll
    for (int bb = 0; bb < 8; ++bb) acc[a][bb] = 0.f;

  const float* w00 = ws + WS_W00;
  const float* w01 = ws + WS_W01;
  const float* w10 = ws + WS_W10;
  const float* w11 = ws + WS_W11;
  const int* i00 = (const int*)ws + WS_I00;
  const int* i01 = (const int*)ws + WS_I01;
  const int* i10 = (const int*)ws + WS_I10;
  const int* i11 = (const int*)ws + WS_I11;
  const float* wfold = ws + WS_WFOLD;

  // B-staging thread-constant pieces: column jB fixed per thread
  const int jB  = t & 127;
  const int r0B = t >> 7;           // rows r0B + 2q
  const int nB  = n0 + jB;
  const int bB  = nB >> 12;
  const float* xb = x + ((long)bB << 20);   // b*256*4096
  // A-staging
  const int jA = t & 63, rA = t >> 6;        // rows rA + 4q

  for (int ch = 0; ch < 144; ++ch) {
    const int k  = ch >> 4;
    const int c0 = (ch & 15) << 4;
    // stage A tile (16 x 64)
#pragma unroll
    for (int q = 0; q < 4; ++q) {
      const int r = rA + (q << 2);
      As[r][jA] = wfold[(((k << 8) + c0 + r) << 8) + o0 + jA];
    }
    // stage B tile (16 x 128): descriptors shared across the 16 channels
    {
      const int d = (k << 14) + nB;
      const float f00 = w00[d], f01 = w01[d], f10 = w10[d], f11 = w11[d];
      const int a00 = i00[d], a01 = i01[d], a10 = i10[d], a11 = i11[d];
#pragma unroll
      for (int q = 0; q < 8; ++q) {
        const int r = r0B + (q << 1);
        const float* pl = xb + ((c0 + r) << 12);
        Bs[r][jB] = f00 * pl[a00] + f01 * pl[a01] + f10 * pl[a10] + f11 * pl[a11];
      }
    }
    __syncthreads();
#pragma unroll
    for (int kk = 0; kk < 16; ++kk) {
      const float4 av = *(const float4*)&As[kk][ty << 2];
      const float4 b0 = *(const float4*)&Bs[kk][tx << 3];
      const float4 b1 = *(const float4*)&Bs[kk][(tx << 3) + 4];
      const float a_[4] = {av.x, av.y, av.z, av.w};
      const float b_[8] = {b0.x, b0.y, b0.z, b0.w, b1.x, b1.y, b1.z, b1.w};
#pragma unroll
      for (int ii = 0; ii < 4; ++ii)
#pragma unroll
        for (int jj = 0; jj < 8; ++jj)
          acc[ii][jj] = fmaf(a_[ii], b_[jj], acc[ii][jj]);
    }
    __syncthreads();
  }

  const float* bfold = ws + WS_BFOLD;
#pragma unroll
  for (int ii = 0; ii < 4; ++ii) {
    const int o = o0 + (ty << 2) + ii;
    const float bf = bfold[o];
#pragma unroll
    for (int jj = 0; jj < 8; ++jj) {
      const int n = n0 + (tx << 3) + jj;
      const int b = n >> 12;
      const int sp = n & 4095;
      out[(((b << 8) + o) << 12) + sp] = fmaxf(acc[ii][jj] + bf, 0.f);
    }
  }
}

// ---------------------------------------------------------------------------
extern "C" void kernel_launch(void* const* d_in, const int* in_sizes, int n_in,
                              void* d_out, int out_size, void* d_ws, size_t ws_size,
                              hipStream_t stream) {
  const float* x     = (const float*)d_in[0];
  const float* wof   = (const float*)d_in[1];
  const float* bof   = (const float*)d_in[2];
  const float* w     = (const float*)d_in[3];
  const float* bias  = (const float*)d_in[4];
  const float* gamma = (const float*)d_in[5];
  const float* beta  = (const float*)d_in[6];
  const float* mean  = (const float*)d_in[7];
  const float* var   = (const float*)d_in[8];
  float* out = (float*)d_out;
  float* ws  = (float*)d_ws;

  // K1: offset conv  (294912 elems)
  hipLaunchKernelGGL(offset_conv_k, dim3(1152), dim3(256), 0, stream,
                     x, wof, bof, ws + WS_OFFS);
  // K2: sample descriptors (147456 elems)
  hipLaunchKernelGGL(make_desc_k, dim3(576), dim3(256), 0, stream,
                     ws + WS_OFFS, ws);
  // K2b: fold weights (589824 elems)
  hipLaunchKernelGGL(fold_weight_k, dim3(2304), dim3(256), 0, stream,
                     w, bias, gamma, beta, mean, var, ws);
  // K3: main fused GEMM. grid (O/64, N/128)
  hipLaunchKernelGGL(deform_gemm_k, dim3(4, 128), dim3(256), 0, stream,
                     x, ws, out);
}

// Round 2
// 724.454 us; speedup vs baseline: 1.3084x; 1.3084x over previous
//
#include <hip/hip_runtime.h>
#include <math.h>

// Problem constants
#define HW    4096          // 64*64
#define NTOT  16384         // B*HW
#define CKDIM 2304          // C*K = 256*9

// ws layout (float-element offsets)
#define WS_OFFS   0         // B*18*HW = 294912
#define WS_W00    294912    // each desc array: 9*16384 = 147456
#define WS_W01    442368
#define WS_W10    589824
#define WS_W11    737280
#define WS_I00    884736
#define WS_I01    1032192
#define WS_I10    1179648
#define WS_I11    1327104
#define WS_WFOLD  1474560   // 2304*256 = 589824
#define WS_BFOLD  2064384   // 256
// total = 2064640 floats = 8,258,560 bytes

// ---------------------------------------------------------------------------
// K1: offset conv. Block = one image row (b, ho): 64 spatial positions.
// 4 waves x 64 lanes; wave wv handles channels [wv*64, wv*64+64).
// Each thread: all 18 output channels for its (ho,wo) -> x loads reused 18x,
// weight indices wave-uniform -> scalar loads. LDS reduce across waves.
// ---------------------------------------------------------------------------
__global__ __launch_bounds__(256) void offset_conv_k(
    const float* __restrict__ x, const float* __restrict__ wof,
    const float* __restrict__ bof, float* __restrict__ offs) {
  __shared__ float red[4][18][64];
  const int t  = threadIdx.x;
  const int b  = blockIdx.x >> 6;
  const int ho = blockIdx.x & 63;
  const int wo = t & 63;
  const int wv = t >> 6;

  float acc[18];
#pragma unroll
  for (int i = 0; i < 18; ++i) acc[i] = 0.f;

  const float* xb = x + ((long)b << 20) + ((long)(wv << 6) << 12);
  const int wl = (wo >= 1) ? -1 : 0;       // clamped left offset
  const int wr = (wo <= 62) ? 1 : 0;       // clamped right offset
  const float vl = (wo >= 1) ? 1.f : 0.f;
  const float vr = (wo <= 62) ? 1.f : 0.f;

  for (int c = 0; c < 64; ++c) {
    const float* xp = xb + (c << 12);
    float v[9];
#pragma unroll
    for (int ky = 0; ky < 3; ++ky) {
      const int y = ho - 1 + ky;
      const int yc = min(max(y, 0), 63);
      const float vy = (y >= 0 && y <= 63) ? 1.f : 0.f;
      const float* row = xp + (yc << 6) + wo;
      v[ky * 3 + 0] = row[wl] * vy * vl;
      v[ky * 3 + 1] = row[0] * vy;
      v[ky * 3 + 2] = row[wr] * vy * vr;
    }
    const int cc = (wv << 6) + c;
#pragma unroll
    for (int oc = 0; oc < 18; ++oc) {
      const float* wp = wof + ((oc << 8) + cc) * 9;   // wave-uniform
#pragma unroll
      for (int kk = 0; kk < 9; ++kk) acc[oc] = fmaf(wp[kk], v[kk], acc[oc]);
    }
  }

#pragma unroll
  for (int oc = 0; oc < 18; ++oc) red[wv][oc][wo] = acc[oc];
  __syncthreads();

  for (int i = t; i < 18 * 64; i += 256) {
    const int oc = i >> 6, w2 = i & 63;
    const float s = red[0][oc][w2] + red[1][oc][w2] + red[2][oc][w2] +
                    red[3][oc][w2] + bof[oc];
    offs[((b * 18 + oc) << 12) + (ho << 6) + w2] = s;
  }
}

// ---------------------------------------------------------------------------
// K2: per-sample descriptors. d = k*16384 + n, n = b*4096 + sp.
// ---------------------------------------------------------------------------
__global__ __launch_bounds__(256) void make_desc_k(
    const float* __restrict__ offs, float* __restrict__ ws) {
  const int d  = blockIdx.x * 256 + threadIdx.x;    // < 147456
  const int k  = d >> 14;
  const int n  = d & 16383;
  const int b  = n >> 12;
  const int sp = n & 4095;
  const int ho = sp >> 6, wo = sp & 63;
  const int ky = k / 3, kx = k - ky * 3;
  const float dy = offs[((b * 18 + (k << 1)) << 12) + sp];
  const float dx = offs[((b * 18 + (k << 1) + 1) << 12) + sp];
  const float py = (float)(ho - 1 + ky) + dy;
  const float px = (float)(wo - 1 + kx) + dx;
  const float y0f = floorf(py), x0f = floorf(px);
  const float ly = py - y0f, lx = px - x0f;
  const int y0 = (int)y0f, x0 = (int)x0f;
  const int y1 = y0 + 1, x1 = x0 + 1;
  const float vy0 = (y0 >= 0 && y0 < 64) ? 1.f : 0.f;
  const float vy1 = (y1 >= 0 && y1 < 64) ? 1.f : 0.f;
  const float vx0 = (x0 >= 0 && x0 < 64) ? 1.f : 0.f;
  const float vx1 = (x1 >= 0 && x1 < 64) ? 1.f : 0.f;
  const int y0c = min(max(y0, 0), 63), y1c = min(max(y1, 0), 63);
  const int x0c = min(max(x0, 0), 63), x1c = min(max(x1, 0), 63);
  ws[WS_W00 + d] = (1.f - ly) * (1.f - lx) * vy0 * vx0;
  ws[WS_W01 + d] = (1.f - ly) * lx * vy0 * vx1;
  ws[WS_W10 + d] = ly * (1.f - lx) * vy1 * vx0;
  ws[WS_W11 + d] = ly * lx * vy1 * vx1;
  int* iws = (int*)ws;
  iws[WS_I00 + d] = (y0c << 6) + x0c;
  iws[WS_I01 + d] = (y0c << 6) + x1c;
  iws[WS_I10 + d] = (y1c << 6) + x0c;
  iws[WS_I11 + d] = (y1c << 6) + x1c;
}

// ---------------------------------------------------------------------------
// K2b: fold weight to [i=k*256+c][o] with BN scale; fold bias.
// ---------------------------------------------------------------------------
__global__ __launch_bounds__(256) void fold_weight_k(
    const float* __restrict__ w, const float* __restrict__ bias,
    const float* __restrict__ gamma, const float* __restrict__ beta,
    const float* __restrict__ mean, const float* __restrict__ var,
    float* __restrict__ ws) {
  const int t = blockIdx.x * 256 + threadIdx.x;     // i*256 + o, i = k*256+c
  const int o = t & 255;
  const int i = t >> 8;
  const int k = i >> 8, c = i & 255;
  const float inv = gamma[o] * rsqrtf(var[o] + 1e-5f);
  ws[WS_WFOLD + t] = w[(((o << 8) + c) * 9) + k] * inv;
  if (t < 256) {
    ws[WS_BFOLD + t] = bias[o] * inv + beta[o] - mean[o] * inv;
  }
}

// ---------------------------------------------------------------------------
// K3: main GEMM with fused deformable im2col.
// Tile: 128 (o) x 128 (n); 256 threads, 8x8 register tile; BK=16.
// Grid = 256 blocks, 1/CU. XCD swizzle: xcd=bid&7 -> 2 XCDs per batch so
// each XCD's x working set (4.2 MB) ~ its L2.
// Split-4 column groups (tx*4 and 64+tx*4) -> 2-way LDS aliasing (free).
// ---------------------------------------------------------------------------
__global__ __launch_bounds__(256) void deform_gemm_k(
    const float* __restrict__ x, const float* __restrict__ ws,
    float* __restrict__ out) {
  __shared__ __align__(16) float As[16][128];
  __shared__ __align__(16) float Bs[16][128];
  const int t     = threadIdx.x;
  const int bid   = blockIdx.x;
  const int xcd   = bid & 7;
  const int slot  = bid >> 3;          // 0..31
  const int batch = xcd >> 1;
  const int o0    = (xcd & 1) << 7;    // 0 or 128
  const int n0    = (batch << 12) + (slot << 7);
  const int tx = t & 15, ty = t >> 4;

  float acc[8][8];
#pragma unroll
  for (int a = 0; a < 8; ++a)
#pragma unroll
    for (int bb = 0; bb < 8; ++bb) acc[a][bb] = 0.f;

  const float* w00 = ws + WS_W00;
  const float* w01 = ws + WS_W01;
  const float* w10 = ws + WS_W10;
  const float* w11 = ws + WS_W11;
  const int* i00 = (const int*)ws + WS_I00;
  const int* i01 = (const int*)ws + WS_I01;
  const int* i10 = (const int*)ws + WS_I10;
  const int* i11 = (const int*)ws + WS_I11;
  const float* wfold = ws + WS_WFOLD;

  const int j  = t & 127;              // staging column (A: o, B: n)
  const int r2 = t >> 7;               // staging row parity
  const int nB = n0 + j;
  const float* xb = x + ((long)batch << 20);

  for (int ch = 0; ch < 144; ++ch) {
    const int k  = ch >> 4;
    const int c0 = (ch & 15) << 4;
    // stage A tile (16 x 128): coalesced from wfold
#pragma unroll
    for (int q = 0; q < 8; ++q) {
      const int r = r2 + (q << 1);
      As[r][j] = wfold[(((k << 8) + c0 + r) << 8) + o0 + j];
    }
    // stage B tile (16 x 128): one descriptor reused across 16 channels
    {
      const int d = (k << 14) + nB;
      const float f00 = w00[d], f01 = w01[d], f10 = w10[d], f11 = w11[d];
      const int a00 = i00[d], a01 = i01[d], a10 = i10[d], a11 = i11[d];
#pragma unroll
      for (int q = 0; q < 8; ++q) {
        const int r = r2 + (q << 1);
        const float* pl = xb + ((c0 + r) << 12);
        Bs[r][j] = f00 * pl[a00] + f01 * pl[a01] + f10 * pl[a10] + f11 * pl[a11];
      }
    }
    __syncthreads();
#pragma unroll
    for (int kk = 0; kk < 16; ++kk) {
      const float4 a0 = *(const float4*)&As[kk][ty << 2];
      const float4 a1 = *(const float4*)&As[kk][64 + (ty << 2)];
      const float4 b0 = *(const float4*)&Bs[kk][tx << 2];
      const float4 b1 = *(const float4*)&Bs[kk][64 + (tx << 2)];
      const float a_[8] = {a0.x, a0.y, a0.z, a0.w, a1.x, a1.y, a1.z, a1.w};
      const float b_[8] = {b0.x, b0.y, b0.z, b0.w, b1.x, b1.y, b1.z, b1.w};
#pragma unroll
      for (int ii = 0; ii < 8; ++ii)
#pragma unroll
        for (int jj = 0; jj < 8; ++jj)
          acc[ii][jj] = fmaf(a_[ii], b_[jj], acc[ii][jj]);
    }
    __syncthreads();
  }

  const float* bfold = ws + WS_BFOLD;
  const int spb = (n0 & 4095);
#pragma unroll
  for (int ii = 0; ii < 8; ++ii) {
    const int o = o0 + (ty << 2) + (ii & 3) + ((ii >> 2) << 6);
    const float bf = bfold[o];
    float* op = out + (((long)((batch << 8) + o)) << 12);
#pragma unroll
    for (int g = 0; g < 2; ++g) {
      const int sp = spb + (tx << 2) + (g << 6);
      float4 v;
      v.x = fmaxf(acc[ii][g * 4 + 0] + bf, 0.f);
      v.y = fmaxf(acc[ii][g * 4 + 1] + bf, 0.f);
      v.z = fmaxf(acc[ii][g * 4 + 2] + bf, 0.f);
      v.w = fmaxf(acc[ii][g * 4 + 3] + bf, 0.f);
      *(float4*)&op[sp] = v;
    }
  }
}

// ---------------------------------------------------------------------------
extern "C" void kernel_launch(void* const* d_in, const int* in_sizes, int n_in,
                              void* d_out, int out_size, void* d_ws, size_t ws_size,
                              hipStream_t stream) {
  const float* x     = (const float*)d_in[0];
  const float* wof   = (const float*)d_in[1];
  const float* bof   = (const float*)d_in[2];
  const float* w     = (const float*)d_in[3];
  const float* bias  = (const float*)d_in[4];
  const float* gamma = (const float*)d_in[5];
  const float* beta  = (const float*)d_in[6];
  const float* mean  = (const float*)d_in[7];
  const float* var   = (const float*)d_in[8];
  float* out = (float*)d_out;
  float* ws  = (float*)d_ws;

  // K1: offset conv (256 blocks = 4 batches x 64 rows)
  hipLaunchKernelGGL(offset_conv_k, dim3(256), dim3(256), 0, stream,
                     x, wof, bof, ws + WS_OFFS);
  // K2: sample descriptors (147456 elems)
  hipLaunchKernelGGL(make_desc_k, dim3(576), dim3(256), 0, stream,
                     ws + WS_OFFS, ws);
  // K2b: fold weights (589824 elems)
  hipLaunchKernelGGL(fold_weight_k, dim3(2304), dim3(256), 0, stream,
                     w, bias, gamma, beta, mean, var, ws);
  // K3: main fused GEMM, 256 blocks with XCD swizzle
  hipLaunchKernelGGL(deform_gemm_k, dim3(256), dim3(256), 0, stream,
                     x, ws, out);
}

// Round 3
// 357.935 us; speedup vs baseline: 2.6482x; 2.0240x over previous
//
#include <hip/hip_runtime.h>
#include <math.h>

typedef __attribute__((ext_vector_type(8))) short b8;
typedef __attribute__((ext_vector_type(4))) float f4;

// ws layout (float-element offsets)
#define WS_OFFS   0         // 294912
#define WS_W00    294912
#define WS_W01    442368
#define WS_W10    589824
#define WS_W11    737280
#define WS_I00    884736
#define WS_I01    1032192
#define WS_I10    1179648
#define WS_I11    1327104
#define WS_AFRAG  1474560   // bf16[589824] == 294912 floats
#define WS_BFOLD  1769472   // 256 floats
// total 1769728 floats = 7.08 MB

__device__ inline ushort f2bf(float f) {
  uint u = __float_as_uint(f);
  uint r = (u + 0x7FFFu + ((u >> 16) & 1u)) >> 16;   // RNE
  return (ushort)r;
}

// ---------------------------------------------------------------------------
// P0: prep. 288 blocks x 256 = 73728 threads.
//  (a) zero offs (each thread one float4 -> 294912 floats)
//  (b) fold weight*BN into MFMA A-fragment order, bf16:
//      afrag[((ch*16+ot)*64+l)*8+j] = w[o][c][k]*inv[o],
//      o=ot*16+(l&15), k=ch>>3, c=((ch&7)<<5)+((l>>4)<<3)+j
//  (c) bfold
// ---------------------------------------------------------------------------
__global__ __launch_bounds__(256) void prep_k(
    const float* __restrict__ w, const float* __restrict__ bias,
    const float* __restrict__ gamma, const float* __restrict__ beta,
    const float* __restrict__ mean, const float* __restrict__ var,
    float* __restrict__ ws) {
  const int tid = blockIdx.x * 256 + threadIdx.x;    // < 73728
  // (a) zero offsets accumulator
  *(f4*)(ws + WS_OFFS + tid * 4) = f4{0.f, 0.f, 0.f, 0.f};
  // (b) A-fragment pack
  const int l  = tid & 63;
  const int ot = (tid >> 6) & 15;
  const int ch = tid >> 10;          // 0..71
  const int o  = (ot << 4) + (l & 15);
  const int k  = ch >> 3;
  const int cb = ((ch & 7) << 5) + ((l >> 4) << 3);
  const float inv = gamma[o] * rsqrtf(var[o] + 1e-5f);
  ushort u[8];
#pragma unroll
  for (int j = 0; j < 8; ++j)
    u[j] = f2bf(w[((o << 8) + cb + j) * 9 + k] * inv);
  b8 pk;
#pragma unroll
  for (int j = 0; j < 8; ++j) pk[j] = (short)u[j];
  *(b8*)((short*)(ws + WS_AFRAG) + tid * 8) = pk;
  // (c) folded bias
  if (tid < 256) {
    const float iv = gamma[tid] * rsqrtf(var[tid] + 1e-5f);
    ws[WS_BFOLD + tid] = bias[tid] * iv + beta[tid] - mean[tid] * iv;
  }
}

// ---------------------------------------------------------------------------
// K1: offset conv. 4096 blocks x 64 threads (1 wave).
// bid -> b(2b), ho(6b), c-slice(4b). All weight indices wave-uniform
// (blockIdx/loop only) -> scalar loads. fp32 atomicAdd into zeroed offs.
// ---------------------------------------------------------------------------
__global__ __launch_bounds__(64) void offset_conv_k(
    const float* __restrict__ x, const float* __restrict__ wof,
    float* __restrict__ offs) {
  const int bid = blockIdx.x;
  const int b   = bid & 3;
  const int ho  = (bid >> 2) & 63;
  const int c0  = (bid >> 8) << 4;   // 0..240
  const int wo  = threadIdx.x;

  float acc[18];
#pragma unroll
  for (int i = 0; i < 18; ++i) acc[i] = 0.f;

  const float* xb = x + ((long)b << 20) + ((long)c0 << 12);
  const int wl = (wo >= 1) ? -1 : 0;
  const int wr = (wo <= 62) ? 1 : 0;
  const float vl = (wo >= 1) ? 1.f : 0.f;
  const float vr = (wo <= 62) ? 1.f : 0.f;

  for (int c = 0; c < 16; ++c) {
    const float* xp = xb + (c << 12);
    float v[9];
#pragma unroll
    for (int ky = 0; ky < 3; ++ky) {
      const int y = ho - 1 + ky;
      const int yc = min(max(y, 0), 63);
      const float vy = (y >= 0 && y <= 63) ? 1.f : 0.f;
      const float* row = xp + (yc << 6) + wo;
      v[ky * 3 + 0] = row[wl] * vy * vl;
      v[ky * 3 + 1] = row[0] * vy;
      v[ky * 3 + 2] = row[wr] * vy * vr;
    }
    const int cc = c0 + c;             // uniform
#pragma unroll
    for (int oc = 0; oc < 18; ++oc) {
      const float* wp = wof + ((oc << 8) + cc) * 9;   // uniform -> s_load
#pragma unroll
      for (int kk = 0; kk < 9; ++kk) acc[oc] = fmaf(wp[kk], v[kk], acc[oc]);
    }
  }
#pragma unroll
  for (int oc = 0; oc < 18; ++oc)
    atomicAdd(&offs[((b * 18 + oc) << 12) + (ho << 6) + wo], acc[oc]);
}

// ---------------------------------------------------------------------------
// K2: per-sample descriptors (bias folded in here). d = k*16384 + n.
// ---------------------------------------------------------------------------
__global__ __launch_bounds__(256) void make_desc_k(
    const float* __restrict__ offs, const float* __restrict__ bof,
    float* __restrict__ ws) {
  const int d  = blockIdx.x * 256 + threadIdx.x;    // < 147456
  const int k  = d >> 14;
  const int n  = d & 16383;
  const int b  = n >> 12;
  const int sp = n & 4095;
  const int ho = sp >> 6, wo = sp & 63;
  const int ky = k / 3, kx = k - ky * 3;
  const float dy = offs[((b * 18 + (k << 1)) << 12) + sp] + bof[k << 1];
  const float dx = offs[((b * 18 + (k << 1) + 1) << 12) + sp] + bof[(k << 1) + 1];
  const float py = (float)(ho - 1 + ky) + dy;
  const float px = (float)(wo - 1 + kx) + dx;
  const float y0f = floorf(py), x0f = floorf(px);
  const float ly = py - y0f, lx = px - x0f;
  const int y0 = (int)y0f, x0 = (int)x0f;
  const int y1 = y0 + 1, x1 = x0 + 1;
  const float vy0 = (y0 >= 0 && y0 < 64) ? 1.f : 0.f;
  const float vy1 = (y1 >= 0 && y1 < 64) ? 1.f : 0.f;
  const float vx0 = (x0 >= 0 && x0 < 64) ? 1.f : 0.f;
  const float vx1 = (x1 >= 0 && x1 < 64) ? 1.f : 0.f;
  const int y0c = min(max(y0, 0), 63), y1c = min(max(y1, 0), 63);
  const int x0c = min(max(x0, 0), 63), x1c = min(max(x1, 0), 63);
  ws[WS_W00 + d] = (1.f - ly) * (1.f - lx) * vy0 * vx0;
  ws[WS_W01 + d] = (1.f - ly) * lx * vy0 * vx1;
  ws[WS_W10 + d] = ly * (1.f - lx) * vy1 * vx0;
  ws[WS_W11 + d] = ly * lx * vy1 * vx1;
  int* iws = (int*)ws;
  iws[WS_I00 + d] = (y0c << 6) + x0c;
  iws[WS_I01 + d] = (y0c << 6) + x1c;
  iws[WS_I10 + d] = (y1c << 6) + x0c;
  iws[WS_I11 + d] = (y1c << 6) + x1c;
}

// ---------------------------------------------------------------------------
// K3: bf16 MFMA GEMM with fused deformable im2col.
// Grid 256: xcd=bid&7, batch=xcd>>1, o0=(xcd&1)<<7, slot=bid>>3.
// Block tile 128(o) x 128(n), CK=2304 in 72 chunks of BK=32.
// A: bf16 frags direct from global (L2). B: gather->bf16 into double-buffered
// LDS [128][40] (2-way-free banks). Wave tile 64x64: 16 mfma_16x16x32/iter.
// ---------------------------------------------------------------------------
__global__ __launch_bounds__(256) void deform_gemm_k(
    const float* __restrict__ x, const float* __restrict__ ws,
    float* __restrict__ out) {
  __shared__ ushort Bs[2][128][40];
  const int t     = threadIdx.x;
  const int bid   = blockIdx.x;
  const int xcd   = bid & 7;
  const int batch = xcd >> 1;
  const int o0    = (xcd & 1) << 7;
  const int slot  = bid >> 3;            // 0..31
  const int spb   = slot << 7;           // n0 within batch
  const int l     = t & 63;
  const int wv    = t >> 6;

  // staging ids
  const int sn    = t & 127;             // B column 0..127
  const int chalf = t >> 7;              // c-half 0/1
  const int nd    = (batch << 12) + spb + sn;  // global n for descriptors
  const float* xb = x + ((long)batch << 20);

  const float* w00 = ws + WS_W00;
  const float* w01 = ws + WS_W01;
  const float* w10 = ws + WS_W10;
  const float* w11 = ws + WS_W11;
  const int* i00 = (const int*)ws + WS_I00;
  const int* i01 = (const int*)ws + WS_I01;
  const int* i10 = (const int*)ws + WS_I10;
  const int* i11 = (const int*)ws + WS_I11;
  const short* af = (const short*)(ws + WS_AFRAG);

  // wave compute ids
  const int ow    = o0 + ((wv >> 1) << 6);   // wave o base
  const int nwsub = (wv & 1) << 6;           // wave n base (within 128)
  const int otb   = ow >> 4;                 // first of 4 o-tiles

  f4 acc[4][4];
#pragma unroll
  for (int i = 0; i < 4; ++i)
#pragma unroll
    for (int j = 0; j < 4; ++j) acc[i][j] = f4{0.f, 0.f, 0.f, 0.f};

  float fw0, fw1, fw2, fw3;
  int   a0_, a1_, a2_, a3_;
  b8 aA[4], aN[4];

#define LOAD_DESC(K_) do { const int d_ = ((K_) << 14) + nd;                 \
    fw0 = w00[d_]; fw1 = w01[d_]; fw2 = w10[d_]; fw3 = w11[d_];              \
    a0_ = i00[d_]; a1_ = i01[d_]; a2_ = i10[d_]; a3_ = i11[d_]; } while (0)

#define STAGE(CH_, BUF_) do {                                                \
    const int c0_ = (((CH_) & 7) << 5) + (chalf << 4);                       \
    float v_[16];                                                            \
    _Pragma("unroll")                                                        \
    for (int q = 0; q < 16; ++q) {                                           \
      const float* pl_ = xb + ((c0_ + q) << 12);                             \
      v_[q] = fw0 * pl_[a0_] + fw1 * pl_[a1_] + fw2 * pl_[a2_] + fw3 * pl_[a3_]; \
    }                                                                        \
    b8 p0_, p1_;                                                             \
    _Pragma("unroll")                                                        \
    for (int q = 0; q < 8; ++q) { p0_[q] = (short)f2bf(v_[q]);               \
                                  p1_[q] = (short)f2bf(v_[q + 8]); }         \
    *(b8*)&Bs[BUF_][sn][chalf << 4] = p0_;                                   \
    *(b8*)&Bs[BUF_][sn][(chalf << 4) + 8] = p1_; } while (0)

#define LOADA(CH_, DST_) do {                                                \
    _Pragma("unroll")                                                        \
    for (int i = 0; i < 4; ++i)                                              \
      DST_[i] = *(const b8*)(af + ((((CH_) * 16 + otb + i) << 6) + l) * 8);  \
  } while (0)

  LOAD_DESC(0);
  STAGE(0, 0);
  LOADA(0, aA);
  __syncthreads();

  for (int ch = 0; ch < 72; ++ch) {
    const int cur = ch & 1;
    if (ch < 71) {
      const int chn = ch + 1;
      if ((chn & 7) == 0) LOAD_DESC(chn >> 3);
      STAGE(chn, cur ^ 1);
      LOADA(chn, aN);
    }
    b8 bB[4];
#pragma unroll
    for (int nt = 0; nt < 4; ++nt)
      bB[nt] = *(const b8*)&Bs[cur][nwsub + (nt << 4) + (l & 15)][(l >> 4) << 3];
#pragma unroll
    for (int mt = 0; mt < 4; ++mt)
#pragma unroll
      for (int nt = 0; nt < 4; ++nt)
        acc[mt][nt] = __builtin_amdgcn_mfma_f32_16x16x32_bf16(
            aA[mt], bB[nt], acc[mt][nt], 0, 0, 0);
#pragma unroll
    for (int i = 0; i < 4; ++i) aA[i] = aN[i];
    __syncthreads();
  }

  const float* bfold = ws + WS_BFOLD;
  const int q4 = (l >> 4) << 2;
#pragma unroll
  for (int mt = 0; mt < 4; ++mt) {
    const int ob = ow + (mt << 4) + q4;
    const f4 bf = *(const f4*)&bfold[ob];
#pragma unroll
    for (int nt = 0; nt < 4; ++nt) {
      const int n_sp = spb + nwsub + (nt << 4) + (l & 15);
#pragma unroll
      for (int r = 0; r < 4; ++r) {
        const int o = ob + r;
        out[(((batch << 8) + o) << 12) + n_sp] =
            fmaxf(acc[mt][nt][r] + bf[r], 0.f);
      }
    }
  }
}

// ---------------------------------------------------------------------------
extern "C" void kernel_launch(void* const* d_in, const int* in_sizes, int n_in,
                              void* d_out, int out_size, void* d_ws, size_t ws_size,
                              hipStream_t stream) {
  const float* x     = (const float*)d_in[0];
  const float* wof   = (const float*)d_in[1];
  const float* bof   = (const float*)d_in[2];
  const float* w     = (const float*)d_in[3];
  const float* bias  = (const float*)d_in[4];
  const float* gamma = (const float*)d_in[5];
  const float* beta  = (const float*)d_in[6];
  const float* mean  = (const float*)d_in[7];
  const float* var   = (const float*)d_in[8];
  float* out = (float*)d_out;
  float* ws  = (float*)d_ws;

  hipLaunchKernelGGL(prep_k, dim3(288), dim3(256), 0, stream,
                     w, bias, gamma, beta, mean, var, ws);
  hipLaunchKernelGGL(offset_conv_k, dim3(4096), dim3(64), 0, stream,
                     x, wof, ws + WS_OFFS);
  hipLaunchKernelGGL(make_desc_k, dim3(576), dim3(256), 0, stream,
                     ws + WS_OFFS, bof, ws);
  hipLaunchKernelGGL(deform_gemm_k, dim3(256), dim3(256), 0, stream,
                     x, ws, out);
}

// Round 4
// 314.528 us; speedup vs baseline: 3.0137x; 1.1380x over previous
//
#include <hip/hip_runtime.h>
#include <math.h>

typedef __attribute__((ext_vector_type(8))) short b8;
typedef __attribute__((ext_vector_type(4))) float f4;

// ws layout (float-element offsets)
#define WS_OFFS   0                 // 2 halves x 294912 partials
#define WS_W00    589824            // g00
#define WS_W01    737280            // g01
#define WS_W10    884736            // g10
#define WS_W11    1032192           // g11
#define WS_I00    1179648           // p0 = (y0c<<6)+xl
#define WS_I01    1327104           // p1 = (y1c<<6)+xl
#define WS_AFRAG  1474560           // bf16[589824]
#define WS_BFOLD  1769472           // 256
// total 1769728 floats = 7.08 MB

__device__ inline ushort f2bf(float f) {
  uint u = __float_as_uint(f);
  return (ushort)((u + 0x7FFFu + ((u >> 16) & 1u)) >> 16);   // RNE
}

// ---------------------------------------------------------------------------
// prep: pack A-fragments (weight*BN, bf16) in iteration order
// iter i in [0,72): cg=i/9 (channel group of 32), kk=i%9 (kernel pos).
// afrag[((i*16+ot)*64+l)*8+j] = w[o][c][kk]*inv[o],
//   o = ot*16 + (l&15),  c = cg*32 + (l>>4)*8 + j      (verified m89 A layout)
// ---------------------------------------------------------------------------
__global__ __launch_bounds__(256) void prep_k(
    const float* __restrict__ w, const float* __restrict__ bias,
    const float* __restrict__ gamma, const float* __restrict__ beta,
    const float* __restrict__ mean, const float* __restrict__ var,
    float* __restrict__ ws) {
  const int tid = blockIdx.x * 256 + threadIdx.x;    // < 73728
  const int l  = tid & 63;
  const int ot = (tid >> 6) & 15;
  const int i  = tid >> 10;          // 0..71
  const int cg = i / 9;
  const int kk = i - cg * 9;
  const int o  = (ot << 4) + (l & 15);
  const int cb = (cg << 5) + ((l >> 4) << 3);
  const float inv = gamma[o] * rsqrtf(var[o] + 1e-5f);
  b8 pk;
#pragma unroll
  for (int j = 0; j < 8; ++j)
    pk[j] = (short)f2bf(w[((o << 8) + cb + j) * 9 + kk] * inv);
  *(b8*)((short*)(ws + WS_AFRAG) + tid * 8) = pk;
  if (tid < 256) {
    const float iv = gamma[tid] * rsqrtf(var[tid] + 1e-5f);
    ws[WS_BFOLD + tid] = bias[tid] * iv + beta[tid] - mean[tid] * iv;
  }
}

// ---------------------------------------------------------------------------
// K1: offset conv partials, NO atomics. grid 512 = half(2) x ho(64) x b(4).
// Block: 4 waves, wave wv covers channels half*128 + wv*32 + [0,32).
// Per channel: 3 coalesced row loads (vy folded), neighbors via __shfl,
// wave-uniform weight s_loads. LDS reduce across waves -> partial store.
// ---------------------------------------------------------------------------
__global__ __launch_bounds__(256) void offset_conv_k(
    const float* __restrict__ x, const float* __restrict__ wof,
    float* __restrict__ ws) {
  __shared__ float red[4][18][64];
  const int bid  = blockIdx.x;
  const int half = bid & 1;
  const int ho   = (bid >> 1) & 63;
  const int b    = bid >> 7;
  const int t    = threadIdx.x;
  const int wo   = t & 63;
  const int wv   = __builtin_amdgcn_readfirstlane(t >> 6);

  float acc[18];
#pragma unroll
  for (int i = 0; i < 18; ++i) acc[i] = 0.f;

  const float vl = (wo >= 1) ? 1.f : 0.f;
  const float vr = (wo <= 62) ? 1.f : 0.f;
  const int yc0 = max(ho - 1, 0), yc2 = min(ho + 1, 63);
  const float vy0 = (ho >= 1) ? 1.f : 0.f;
  const float vy2 = (ho <= 62) ? 1.f : 0.f;
  const int cbase = (half << 7) + (wv << 5);
  const float* xb = x + ((long)b << 20) + ((long)cbase << 12);

  for (int c = 0; c < 32; ++c) {
    const float* xp = xb + (c << 12);
    float m0 = xp[(yc0 << 6) + wo] * vy0;
    float m1 = xp[(ho << 6) + wo];
    float m2 = xp[(yc2 << 6) + wo] * vy2;
    float v[9];
    v[0] = __shfl_up(m0, 1) * vl;  v[1] = m0;  v[2] = __shfl_down(m0, 1) * vr;
    v[3] = __shfl_up(m1, 1) * vl;  v[4] = m1;  v[5] = __shfl_down(m1, 1) * vr;
    v[6] = __shfl_up(m2, 1) * vl;  v[7] = m2;  v[8] = __shfl_down(m2, 1) * vr;
    const int cc = cbase + c;      // uniform
#pragma unroll
    for (int oc = 0; oc < 18; ++oc) {
      const float* wp = wof + ((oc << 8) + cc) * 9;   // uniform -> s_load
#pragma unroll
      for (int kk = 0; kk < 9; ++kk) acc[oc] = fmaf(wp[kk], v[kk], acc[oc]);
    }
  }
#pragma unroll
  for (int oc = 0; oc < 18; ++oc) red[wv][oc][wo] = acc[oc];
  __syncthreads();
  for (int i = t; i < 18 * 64; i += 256) {
    const int oc = i >> 6, w2 = i & 63;
    const float s = red[0][oc][w2] + red[1][oc][w2] +
                    red[2][oc][w2] + red[3][oc][w2];
    ws[WS_OFFS + half * 294912 + ((b * 18 + oc) << 12) + (ho << 6) + w2] = s;
  }
}

// ---------------------------------------------------------------------------
// K2: descriptors in pair form. Sums the two K1 halves + offset bias.
// Output per (k,n): g00,g01 (weights for x-pair at row y0c, cols xl,xl+1),
// g10,g11 (row y1c), p0=(y0c<<6)+xl, p1=(y1c<<6)+xl, xl=min(x0c,62).
// ---------------------------------------------------------------------------
__global__ __launch_bounds__(256) void make_desc_k(
    const float* __restrict__ bof, float* __restrict__ ws) {
  const int d  = blockIdx.x * 256 + threadIdx.x;    // < 147456
  const int k  = d >> 14;
  const int n  = d & 16383;
  const int b  = n >> 12;
  const int sp = n & 4095;
  const int ho = sp >> 6, wo = sp & 63;
  const int ky = k / 3, kx = k - ky * 3;
  const int i0 = ((b * 18 + (k << 1)) << 12) + sp;
  const int i1 = ((b * 18 + (k << 1) + 1) << 12) + sp;
  const float dy = ws[WS_OFFS + i0] + ws[WS_OFFS + 294912 + i0] + bof[k << 1];
  const float dx = ws[WS_OFFS + i1] + ws[WS_OFFS + 294912 + i1] + bof[(k << 1) + 1];
  const float py = (float)(ho - 1 + ky) + dy;
  const float px = (float)(wo - 1 + kx) + dx;
  const float y0f = floorf(py), x0f = floorf(px);
  const float ly = py - y0f, lx = px - x0f;
  const int y0 = (int)y0f, x0 = (int)x0f;
  const int y1 = y0 + 1, x1 = x0 + 1;
  const float vy0 = (y0 >= 0 && y0 < 64) ? 1.f : 0.f;
  const float vy1 = (y1 >= 0 && y1 < 64) ? 1.f : 0.f;
  const float vx0 = (x0 >= 0 && x0 < 64) ? 1.f : 0.f;
  const float vx1 = (x1 >= 0 && x1 < 64) ? 1.f : 0.f;
  const int y0c = min(max(y0, 0), 63), y1c = min(max(y1, 0), 63);
  const int x0c = min(max(x0, 0), 63), x1c = min(max(x1, 0), 63);
  const float w00 = (1.f - ly) * (1.f - lx) * vy0 * vx0;
  const float w01 = (1.f - ly) * lx * vy0 * vx1;
  const float w10 = ly * (1.f - lx) * vy1 * vx0;
  const float w11 = ly * lx * vy1 * vx1;
  const int xl = min(x0c, 62);
  const int s0 = x0c - xl;           // 0/1
  const int s1 = x1c - xl;           // 0/1
  const float g00 = (s0 == 0 ? w00 : 0.f) + (s1 == 0 ? w01 : 0.f);
  const float g01 = (s0 == 1 ? w00 : 0.f) + (s1 == 1 ? w01 : 0.f);
  const float g10 = (s0 == 0 ? w10 : 0.f) + (s1 == 0 ? w11 : 0.f);
  const float g11 = (s0 == 1 ? w10 : 0.f) + (s1 == 1 ? w11 : 0.f);
  ws[WS_W00 + d] = g00;
  ws[WS_W01 + d] = g01;
  ws[WS_W10 + d] = g10;
  ws[WS_W11 + d] = g11;
  int* iws = (int*)ws;
  iws[WS_I00 + d] = (y0c << 6) + xl;
  iws[WS_I01 + d] = (y1c << 6) + xl;
}

// ---------------------------------------------------------------------------
// K3: bf16 MFMA GEMM, fused deformable im2col, c-group-outer/k-inner order
// for L1 reuse (32-ch gather window stays L1-resident across 9 k-iters).
// Grid 512: xcd=bid&7 -> batch=xcd>>1, o0=(xcd&1)*128; slot=bid>>3 (64 n).
// Tile 128o x 64n, 4 waves of 64o x 32n. BK=32 (c within group). Dbuf LDS.
// ---------------------------------------------------------------------------
__global__ __launch_bounds__(256, 2) void deform_gemm_k(
    const float* __restrict__ x, const float* __restrict__ ws,
    float* __restrict__ out) {
  __shared__ ushort Bs[2][64][40];
  const int t     = threadIdx.x;
  const int bid   = blockIdx.x;
  const int xcd   = bid & 7;
  const int batch = xcd >> 1;
  const int o0    = (xcd & 1) << 7;
  const int slot  = bid >> 3;            // 0..63
  const int l     = t & 63;
  const int wv    = t >> 6;

  // staging ids: sn = col, cq = channel-quarter (8 ch)
  const int sn = t & 63;
  const int cq = t >> 6;
  const int nd = (batch << 12) + (slot << 6) + sn;
  const float* xb = x + ((long)batch << 20);

  const float* gw0 = ws + WS_W00;
  const float* gw1 = ws + WS_W01;
  const float* gw2 = ws + WS_W10;
  const float* gw3 = ws + WS_W11;
  const int* ip0 = (const int*)ws + WS_I00;
  const int* ip1 = (const int*)ws + WS_I01;
  const short* af = (const short*)(ws + WS_AFRAG);

  // wave compute ids
  const int ow  = o0 + ((wv & 1) << 6);
  const int nw  = (wv >> 1) << 5;
  const int otb = ow >> 4;

  f4 acc[4][2];
#pragma unroll
  for (int i = 0; i < 4; ++i)
#pragma unroll
    for (int j = 0; j < 2; ++j) acc[i][j] = f4{0.f, 0.f, 0.f, 0.f};

  float pg0, pg1, pg2, pg3; int pp0, pp1;   // desc for pending gather iter
  float qg0, qg1, qg2, qg3; int qp0, qp1;   // desc prefetched one further
  b8 aA[4], aN[4];
  float vg[8][4];                           // gathered corners, 8 channels

#define LOAD_DESC(K_, G0,G1,G2,G3,P0,P1) do { const int d_ = ((K_) << 14) + nd; \
    G0 = gw0[d_]; G1 = gw1[d_]; G2 = gw2[d_]; G3 = gw3[d_];                     \
    P0 = ip0[d_]; P1 = ip1[d_]; } while (0)

#define GATHER(CG_) do {                                                        \
    const int c0_ = ((CG_) << 5) + (cq << 3);                                   \
    _Pragma("unroll")                                                           \
    for (int q = 0; q < 8; ++q) {                                               \
      const float* pl_ = xb + ((c0_ + q) << 12);                                \
      vg[q][0] = pl_[pp0]; vg[q][1] = pl_[pp0 + 1];                             \
      vg[q][2] = pl_[pp1]; vg[q][3] = pl_[pp1 + 1];                             \
    } } while (0)

#define COMBINE_STORE(BUF_) do {                                                \
    b8 pk_;                                                                     \
    _Pragma("unroll")                                                           \
    for (int q = 0; q < 8; ++q) {                                               \
      float v_ = pg0 * vg[q][0] + pg1 * vg[q][1] + pg2 * vg[q][2] + pg3 * vg[q][3]; \
      pk_[q] = (short)f2bf(v_);                                                 \
    }                                                                           \
    *(b8*)&Bs[BUF_][sn][cq << 3] = pk_; } while (0)

#define LOADA(I_, DST_) do {                                                    \
    _Pragma("unroll")                                                           \
    for (int m = 0; m < 4; ++m)                                                 \
      DST_[m] = *(const b8*)(af + (((((I_) << 4) + otb + m) << 6) + l) * 8);    \
  } while (0)

  // prologue: iter 0 (cg=0,kk=0)
  LOAD_DESC(0, pg0, pg1, pg2, pg3, pp0, pp1);
  GATHER(0);
  LOAD_DESC(1, qg0, qg1, qg2, qg3, qp0, qp1);   // iter1: cg0,kk1
  COMBINE_STORE(0);
  LOADA(0, aA);
  __syncthreads();

  int cgN = 0, kkN = 1;                // (cg,kk) of iter i+1
  for (int i = 0; i < 72; ++i) {
    const int cur = i & 1;
    if (i < 71) {
      // gather for iter i+1 using prefetched desc (q -> p)
      pg0 = qg0; pg1 = qg1; pg2 = qg2; pg3 = qg3; pp0 = qp0; pp1 = qp1;
      GATHER(cgN);
      LOADA(i + 1, aN);
      if (i < 70) {
        int kk2 = kkN + 1, cg2 = cgN;
        if (kk2 == 9) { kk2 = 0; cg2++; }
        LOAD_DESC(kk2, qg0, qg1, qg2, qg3, qp0, qp1);
      }
    }
    // B fragments from LDS (cur)
    b8 bB[2];
#pragma unroll
    for (int nt = 0; nt < 2; ++nt)
      bB[nt] = *(const b8*)&Bs[cur][nw + (nt << 4) + (l & 15)][(l >> 4) << 3];
#pragma unroll
    for (int mt = 0; mt < 4; ++mt)
#pragma unroll
      for (int nt = 0; nt < 2; ++nt)
        acc[mt][nt] = __builtin_amdgcn_mfma_f32_16x16x32_bf16(
            aA[mt], bB[nt], acc[mt][nt], 0, 0, 0);
    if (i < 71) {
      COMBINE_STORE(cur ^ 1);
#pragma unroll
      for (int m = 0; m < 4; ++m) aA[m] = aN[m];
      kkN++; if (kkN == 9) { kkN = 0; cgN++; }
    }
    __syncthreads();
  }

  const float* bfold = ws + WS_BFOLD;
  const int q4 = (l >> 4) << 2;
#pragma unroll
  for (int mt = 0; mt < 4; ++mt) {
    const int ob = ow + (mt << 4) + q4;
    const f4 bf = *(const f4*)&bfold[ob];
#pragma unroll
    for (int nt = 0; nt < 2; ++nt) {
      const int sp = (slot << 6) + nw + (nt << 4) + (l & 15);
#pragma unroll
      for (int r = 0; r < 4; ++r) {
        const int o = ob + r;
        out[(((batch << 8) + o) << 12) + sp] =
            fmaxf(acc[mt][nt][r] + bf[r], 0.f);
      }
    }
  }
}

// ---------------------------------------------------------------------------
extern "C" void kernel_launch(void* const* d_in, const int* in_sizes, int n_in,
                              void* d_out, int out_size, void* d_ws, size_t ws_size,
                              hipStream_t stream) {
  const float* x     = (const float*)d_in[0];
  const float* wof   = (const float*)d_in[1];
  const float* bof   = (const float*)d_in[2];
  const float* w     = (const float*)d_in[3];
  const float* bias  = (const float*)d_in[4];
  const float* gamma = (const float*)d_in[5];
  const float* beta  = (const float*)d_in[6];
  const float* mean  = (const float*)d_in[7];
  const float* var   = (const float*)d_in[8];
  float* out = (float*)d_out;
  float* ws  = (float*)d_ws;

  hipLaunchKernelGGL(prep_k, dim3(288), dim3(256), 0, stream,
                     w, bias, gamma, beta, mean, var, ws);
  hipLaunchKernelGGL(offset_conv_k, dim3(512), dim3(256), 0, stream,
                     x, wof, ws);
  hipLaunchKernelGGL(make_desc_k, dim3(576), dim3(256), 0, stream,
                     bof, ws);
  hipLaunchKernelGGL(deform_gemm_k, dim3(512), dim3(256), 0, stream,
                     x, ws, out);
}